// Round 7
// baseline (2777.423 us; speedup 1.0000x reference)
//
#include <hip/hip_runtime.h>

#define BB 32
#define TT 1000
#define HH 512
#define G4 2048
#define BTH ((size_t)BB * TT * HH)  // elements per output tensor

typedef short short8 __attribute__((ext_vector_type(8)));
typedef float f32x4 __attribute__((ext_vector_type(4)));

__device__ __forceinline__ unsigned short f2bf(float f) {
    union { float f; unsigned u; } v; v.f = f;
    unsigned r = v.u + 0x7FFF + ((v.u >> 16) & 1);  // RNE; inputs finite
    return (unsigned short)(r >> 16);
}

// rings: u32 words [2 slots][8 groups][32 producers x 64 words]
// word = (bf16(h) << 16) | t  -- self-tagged (R2-proven protocol)
// gring: AGENT-scope (MALL) -- always correct.  lring: sc0 fast path (XCD L2).
#define RING_WORDS (2 * 8 * 32 * 64)   // 32768 u32 = 128KB per ring

__global__ void lstm_init_ring(unsigned* ring) {
    int i = blockIdx.x * 256 + threadIdx.x;
    __hip_atomic_store(ring + i, 0xFFFFFFFFu, __ATOMIC_RELAXED,
                       __HIP_MEMORY_SCOPE_AGENT);
}

// LDS-ordering-only barrier (R4-validated): VMEM stays in flight.
#define LDS_BAR() do {                                      \
    asm volatile("s_waitcnt lgkmcnt(0)" ::: "memory");      \
    __builtin_amdgcn_s_barrier();                           \
    asm volatile("" ::: "memory");                          \
    __builtin_amdgcn_sched_barrier(0);                      \
} while (0)

__global__ void __launch_bounds__(256, 1)
lstm_main(const float* __restrict__ wx, const float* __restrict__ u,
          const float* __restrict__ ub, const float* __restrict__ ht0,
          const float* __restrict__ ct0, float* __restrict__ out,
          unsigned* __restrict__ gring, unsigned* __restrict__ lring)
{
    __shared__ __align__(16) unsigned short lds_h[16 * 512];  // 16KB, XOR-swizzled
    __shared__ float lds_gates[4 * 64];

    const int tid  = threadIdx.x;
    const int bid  = blockIdx.x;
    // XCD-aligned grouping under round-robin dispatch (bid%8 -> XCD).
    // Pure index remap: correctness does NOT depend on the physical mapping
    // (global-ring fallback covers misalignment).
    const int qb   = bid & 7;    // batch group: batches [qb*4, qb*4+4)
    const int cg   = bid >> 3;   // column group: h/gate cols [cg*16, cg*16+16)
    const int lane = tid & 63;
    const int wv   = tid >> 6;

    // ---- zero pad rows 4..15 of lds_h ----
    for (int j = 0; j < 3; ++j) {
        int idx8 = tid + j * 256;
        int r = 4 + (idx8 >> 6);
        int k = (idx8 & 63) * 8;
        short8 z = {0, 0, 0, 0, 0, 0, 0, 0};
        *(short8*)&lds_h[(r * 512 + k) ^ ((r & 7) << 3)] = z;
    }
    // ---- stage initial h (f32 -> bf16) ----
    {
        int r = wv, k = lane * 8;
        const float* src = ht0 + (size_t)(qb * 4 + r) * HH + k;
        float4 v0 = *(const float4*)src;
        float4 v1 = *(const float4*)(src + 4);
        union { short8 v8; unsigned short s[8]; } p;
        p.s[0] = f2bf(v0.x); p.s[1] = f2bf(v0.y); p.s[2] = f2bf(v0.z); p.s[3] = f2bf(v0.w);
        p.s[4] = f2bf(v1.x); p.s[5] = f2bf(v1.y); p.s[6] = f2bf(v1.z); p.s[7] = f2bf(v1.w);
        *(short8*)&lds_h[(r * 512 + k) ^ ((r & 7) << 3)] = p.v8;
    }

    // ---- preload u fragments into registers (loop-invariant) ----
    const int arow = lane & 15, ahi = lane >> 4;
    short8 breg[16];
    {
        const float* bp = u + (size_t)(wv * HH + cg * 16 + arow) * HH + ahi * 8;
#pragma unroll
        for (int kk = 0; kk < 16; ++kk) {
            float4 v0 = *(const float4*)(bp + kk * 32);
            float4 v1 = *(const float4*)(bp + kk * 32 + 4);
            union { short8 v8; unsigned short s[8]; } p;
            p.s[0] = f2bf(v0.x); p.s[1] = f2bf(v0.y); p.s[2] = f2bf(v0.z); p.s[3] = f2bf(v0.w);
            p.s[4] = f2bf(v1.x); p.s[5] = f2bf(v1.y); p.s[6] = f2bf(v1.z); p.s[7] = f2bf(v1.w);
            breg[kk] = p.v8;
        }
    }

    const int gate = lane >> 4;
    const int jc   = lane & 15;
    const float bias_r = ub[gate * HH + cg * 16 + jc];

    float c_reg = 0.f;
    if (lane < 16)
        c_reg = ct0[(size_t)(qb * 4 + wv) * HH + cg * 16 + lane];

    const size_t wx0 = (size_t)(qb * 4 + wv) * TT * G4 + gate * HH + cg * 16 + jc;
    float wx_cur = wx[wx0];
    float wx_nxt = wx[wx0 + G4];

    const size_t ob_gate = (size_t)(2 + gate) * BTH +
                           (size_t)(qb * 4 + wv) * TT * HH + cg * 16 + jc;
    const size_t ob_h = (size_t)(qb * 4 + wv) * TT * HH + cg * 16 + lane;

    const int a_off = arow * 512 + ahi * 8;
    const int a_msk = (arow & 7) << 3;

    const int myp = tid >> 3;            // producer 0..31
    const int mw  = (tid & 7) * 8;       // word offset 0..56
    const int mb  = mw >> 4;
    const int mj  = mw & 15;

    __syncthreads();

    for (int t = 0; t < TT; ++t) {
        // ---- phase 1: acquire h_{t-1}: local sc0 poll, AGENT fallback ----
        if (t > 0 && myp != cg) {
            const unsigned base = ((unsigned)((t - 1) & 1) * 8 + (unsigned)qb) * 2048
                                  + myp * 64 + mw;
            const unsigned long long* gsrc = (const unsigned long long*)(gring + base);
            const unsigned long long* lsrc = (const unsigned long long*)(lring + base);
            const unsigned tg = (unsigned)(t - 1);
            const unsigned long long want =
                (unsigned long long)tg | ((unsigned long long)tg << 32);
            const unsigned long long msk = 0x0000FFFF0000FFFFull;
            unsigned long long q0, q1, q2, q3;
            int tries = 0;
            for (;;) {
                if (tries < 8) {
                    // local fast path: sc0 = stay in this XCD's L2 (~150cy RT).
                    // vmcnt(0) inside the asm: no in-flight regs at exit (R5 lesson).
                    asm volatile(
                        "global_load_dwordx2 %0, %4, off sc0\n\t"
                        "global_load_dwordx2 %1, %4, off offset:8 sc0\n\t"
                        "global_load_dwordx2 %2, %4, off offset:16 sc0\n\t"
                        "global_load_dwordx2 %3, %4, off offset:24 sc0\n\t"
                        "s_waitcnt vmcnt(0)"
                        : "=&v"(q0), "=&v"(q1), "=&v"(q2), "=&v"(q3)
                        : "v"(lsrc) : "memory");
                } else {
                    // R2-proven global path: guaranteed progress on any mapping
                    q0 = __hip_atomic_load(gsrc + 0, __ATOMIC_RELAXED, __HIP_MEMORY_SCOPE_AGENT);
                    q1 = __hip_atomic_load(gsrc + 1, __ATOMIC_RELAXED, __HIP_MEMORY_SCOPE_AGENT);
                    q2 = __hip_atomic_load(gsrc + 2, __ATOMIC_RELAXED, __HIP_MEMORY_SCOPE_AGENT);
                    q3 = __hip_atomic_load(gsrc + 3, __ATOMIC_RELAXED, __HIP_MEMORY_SCOPE_AGENT);
                }
                if (((q0 & msk) == want) & ((q1 & msk) == want) &
                    ((q2 & msk) == want) & ((q3 & msk) == want)) break;
                ++tries;
            }
            union { short8 v8; unsigned u[4]; } pv;
            pv.u[0] = ((unsigned)(q0 >> 16) & 0xFFFFu) | ((unsigned)(q0 >> 48) << 16);
            pv.u[1] = ((unsigned)(q1 >> 16) & 0xFFFFu) | ((unsigned)(q1 >> 48) << 16);
            pv.u[2] = ((unsigned)(q2 >> 16) & 0xFFFFu) | ((unsigned)(q2 >> 48) << 16);
            pv.u[3] = ((unsigned)(q3 >> 16) & 0xFFFFu) | ((unsigned)(q3 >> 48) << 16);
            *(short8*)&lds_h[(mb * 512 + myp * 16 + mj) ^ ((mb & 7) << 3)] = pv.v8;
        }
        __syncthreads();   // S1: full barrier (nothing long in flight here)

        const float wx_use = wx_cur;
        wx_cur = wx_nxt;
        if (t + 2 < TT) wx_nxt = wx[wx0 + (size_t)(t + 2) * G4];   // R2 position

        // ---- phase 2: MFMA (R2-exact) ----
        f32x4 acc0 = {0.f, 0.f, 0.f, 0.f}, acc1 = {0.f, 0.f, 0.f, 0.f};
#pragma unroll
        for (int kk = 0; kk < 8; ++kk) {
            short8 va0 = *(const short8*)&lds_h[(a_off + kk * 32) ^ a_msk];
            short8 va1 = *(const short8*)&lds_h[(a_off + (kk + 8) * 32) ^ a_msk];
            acc0 = __builtin_amdgcn_mfma_f32_16x16x32_bf16(va0, breg[kk], acc0, 0, 0, 0);
            acc1 = __builtin_amdgcn_mfma_f32_16x16x32_bf16(va1, breg[kk + 8], acc1, 0, 0, 0);
        }
        f32x4 g = acc0 + acc1;
        if (lane < 16) {
#pragma unroll
            for (int rr = 0; rr < 4; ++rr)
                lds_gates[rr * 64 + wv * 16 + lane] = g[rr];
        }
        LDS_BAR();   // S2: LDS-only barrier -> wx prefetch NOT drained here

        // ---- phase 3: activations, c/h update, publish (R2-exact + dual pub) ----
        float gv = lds_gates[wv * 64 + lane] + wx_use + bias_r;
        float xs = (gate == 2) ? 2.f * gv : gv;
        float s  = 1.f / (1.f + __expf(-xs));
        float act = (gate == 2) ? 2.f * s - 1.f : s;  // tanh = 2*sigmoid(2x)-1

        float af = __shfl(act, (lane & 15) + 16, 64);
        float ag = __shfl(act, (lane & 15) + 32, 64);
        float ao = __shfl(act, (lane & 15) + 48, 64);
        if (lane < 16) {
            c_reg = af * c_reg + act * ag;
            float e2 = __expf(-2.f * c_reg);
            float th = 2.f / (1.f + e2) - 1.f;
            float hn = ao * th;
            unsigned short hb = f2bf(hn);
            unsigned pk = ((unsigned)hb << 16) | (unsigned)t;
            const unsigned pb = ((unsigned)(t & 1) * 8 + (unsigned)qb) * 2048 +
                                cg * 64 + wv * 16 + lane;
            // local publish first (fast path), then the proven global publish
            asm volatile("global_store_dword %0, %1, off sc0"
                         :: "v"(lring + pb), "v"(pk) : "memory");
            __hip_atomic_store(gring + pb, pk, __ATOMIC_RELAXED,
                               __HIP_MEMORY_SCOPE_AGENT);
            lds_h[(wv * 512 + cg * 16 + lane) ^ ((wv & 7) << 3)] = hb;
            out[ob_h + (size_t)t * HH] = hn;
            out[BTH + ob_h + (size_t)t * HH] = c_reg;
        }
        out[ob_gate + (size_t)t * HH] = act;
    }
}

extern "C" void kernel_launch(void* const* d_in, const int* in_sizes, int n_in,
                              void* d_out, int out_size, void* d_ws, size_t ws_size,
                              hipStream_t stream) {
    const float* wx = (const float*)d_in[0];
    const float* u  = (const float*)d_in[1];
    const float* ub = (const float*)d_in[2];
    const float* ht = (const float*)d_in[3];
    const float* ct = (const float*)d_in[4];
    float* out = (float*)d_out;
    unsigned* gring = (unsigned*)d_ws;                       // 128KB (proven)
    // local ring only if workspace provably fits; else alias (degrades to R2 path)
    const int dual = (ws_size >= (size_t)2 * RING_WORDS * 4);
    unsigned* lring = dual ? (gring + RING_WORDS) : gring;
    const int init_words = dual ? 2 * RING_WORDS : RING_WORDS;

    lstm_init_ring<<<init_words / 256, 256, 0, stream>>>(gring);

    void* args[] = {(void*)&wx, (void*)&u, (void*)&ub, (void*)&ht,
                    (void*)&ct, (void*)&out, (void*)&gring, (void*)&lring};
    hipLaunchCooperativeKernel((void*)lstm_main, dim3(256), dim3(256), args, 0, stream);
}